// Round 1
// baseline (162.123 us; speedup 1.0000x reference)
//
#include <hip/hip_runtime.h>

#define NTOT 2336
#define NS   2048
#define NT   288
#define DD   32
#define BATCH 4
#define S2   ((size_t)NTOT * NTOT)
#define LDSS 68   // LDS row stride (floats): 64 + 4 pad, keeps 16B alignment, breaks bank conflicts

// ws layout (floats):
//   nv1   : [4][2048][32] @ 0
//   nv2   : [4][2048][32] @ 262144
//   s_st1 : [4][2048]     @ 524288   (includes +b_st)
//   s_st2 : [4][288]      @ 532480
//   s_ts1 : [4][288]      @ 533632   (includes +b_ts)
//   s_ts2 : [4][2048]     @ 534784
// total 542976 floats = 2.17 MB
#define WS_NV2   (BATCH * NS * DD)
#define WS_SST1  (2 * BATCH * NS * DD)
#define WS_SST2  (WS_SST1 + BATCH * NS)
#define WS_STS1  (WS_SST2 + BATCH * NT)
#define WS_STS2  (WS_STS1 + BATCH * NT)

__device__ __forceinline__ float fast_tanh(float x) {
    float e = __expf(2.0f * x);
    return 1.0f - 2.0f * __builtin_amdgcn_rcpf(e + 1.0f);
}
// tanh(relu(x))
__device__ __forceinline__ float f_out(float x) {
    return fast_tanh(fmaxf(x, 0.0f));
}

// ---------------------------------------------------------------------------
// Precompute: nv1/nv2 (tanh(3 * S @ W^T)) and the four pair-linear vectors.
// ---------------------------------------------------------------------------
__global__ void precompute_kernel(const float* __restrict__ S,
                                  const float* __restrict__ T,
                                  const float* __restrict__ W1,
                                  const float* __restrict__ W2,
                                  const float* __restrict__ w_st,
                                  const float* __restrict__ b_st,
                                  const float* __restrict__ w_ts,
                                  const float* __restrict__ b_ts,
                                  float* __restrict__ ws) {
    __shared__ float sW1[DD * DD];
    __shared__ float sW2[DD * DD];
    __shared__ float swst[2 * DD];
    __shared__ float swts[2 * DD];
    int tid = threadIdx.x;
    for (int i = tid; i < DD * DD; i += 256) { sW1[i] = W1[i]; sW2[i] = W2[i]; }
    if (tid < 2 * DD) { swst[tid] = w_st[tid]; swts[tid] = w_ts[tid]; }
    __syncthreads();

    float* nv1   = ws;
    float* nv2   = ws + WS_NV2;
    float* s_st1 = ws + WS_SST1;
    float* s_st2 = ws + WS_SST2;
    float* s_ts1 = ws + WS_STS1;
    float* s_ts2 = ws + WS_STS2;

    int idx = blockIdx.x * 256 + tid;
    if (idx < BATCH * NS) {
        // one spatial row: nv1 row, nv2 row, s_st1, s_ts2
        const float* row = S + idx * DD;
        float r[DD];
        #pragma unroll
        for (int q = 0; q < 8; q++) {
            float4 v = ((const float4*)row)[q];
            r[q * 4 + 0] = v.x; r[q * 4 + 1] = v.y;
            r[q * 4 + 2] = v.z; r[q * 4 + 3] = v.w;
        }
        float o1[DD], o2[DD];
        for (int d = 0; d < DD; d++) {
            float a1 = 0.f, a2 = 0.f;
            #pragma unroll
            for (int k = 0; k < DD; k++) {
                a1 = fmaf(r[k], sW1[d * DD + k], a1);
                a2 = fmaf(r[k], sW2[d * DD + k], a2);
            }
            o1[d] = fast_tanh(3.0f * a1);
            o2[d] = fast_tanh(3.0f * a2);
        }
        #pragma unroll
        for (int q = 0; q < 8; q++) {
            float4 v1 = { o1[q*4], o1[q*4+1], o1[q*4+2], o1[q*4+3] };
            float4 v2 = { o2[q*4], o2[q*4+1], o2[q*4+2], o2[q*4+3] };
            ((float4*)(nv1 + idx * DD))[q] = v1;
            ((float4*)(nv2 + idx * DD))[q] = v2;
        }
        float d1 = 0.f, d2 = 0.f;
        #pragma unroll
        for (int k = 0; k < DD; k++) {
            d1 = fmaf(r[k], swst[k], d1);
            d2 = fmaf(r[k], swts[DD + k], d2);
        }
        s_st1[idx] = d1 + b_st[0];
        s_ts2[idx] = d2;
    } else if (idx < BATCH * NS + BATCH * NT) {
        int t = idx - BATCH * NS;
        const float* row = T + t * DD;
        float r[DD];
        #pragma unroll
        for (int q = 0; q < 8; q++) {
            float4 v = ((const float4*)row)[q];
            r[q * 4 + 0] = v.x; r[q * 4 + 1] = v.y;
            r[q * 4 + 2] = v.z; r[q * 4 + 3] = v.w;
        }
        float d1 = 0.f, d2 = 0.f;
        #pragma unroll
        for (int k = 0; k < DD; k++) {
            d1 = fmaf(r[k], swst[DD + k], d1);
            d2 = fmaf(r[k], swts[k], d2);
        }
        s_st2[t] = d1;
        s_ts1[t] = d2 + b_ts[0];
    }
}

// ---------------------------------------------------------------------------
// ss block: x = nv1_i . nv2_j - nv2_i . nv1_j  (== m - m^T without transpose)
// out[i,j] = tanh(relu(tanh(x)));  mirror out[j,i] = tanh(relu(-tanh(x)))
// Upper-triangular tile pairs only; 64x64 tiles, 16x16 threads x 4x4 micro.
// LDS transposed [k][row] so inner-loop reads are ds_read_b128.
// ---------------------------------------------------------------------------
__global__ __launch_bounds__(256, 4) void ss_kernel(const float* __restrict__ nv1,
                                                    const float* __restrict__ nv2,
                                                    float* __restrict__ out) {
    int ti = blockIdx.x, tj = blockIdx.y, b = blockIdx.z;
    if (tj < ti) return;

    __shared__ __align__(16) float A1[DD][LDSS];  // nv1 rows of tile ti
    __shared__ __align__(16) float A2[DD][LDSS];  // nv2 rows of tile ti
    __shared__ __align__(16) float B1[DD][LDSS];  // nv2 rows of tile tj
    __shared__ __align__(16) float B2[DD][LDSS];  // nv1 rows of tile tj

    int tid = threadIdx.x;
    const float* src1 = nv1 + ((size_t)b * NS + ti * 64) * DD;
    const float* src2 = nv2 + ((size_t)b * NS + ti * 64) * DD;
    const float* src3 = nv2 + ((size_t)b * NS + tj * 64) * DD;
    const float* src4 = nv1 + ((size_t)b * NS + tj * 64) * DD;

    #pragma unroll
    for (int rep = 0; rep < 2; rep++) {
        int q   = rep * 256 + tid;
        int row = q >> 3;
        int k4  = (q & 7) * 4;
        float4 v;
        v = *(const float4*)(src1 + row * DD + k4);
        A1[k4+0][row] = v.x; A1[k4+1][row] = v.y; A1[k4+2][row] = v.z; A1[k4+3][row] = v.w;
        v = *(const float4*)(src2 + row * DD + k4);
        A2[k4+0][row] = v.x; A2[k4+1][row] = v.y; A2[k4+2][row] = v.z; A2[k4+3][row] = v.w;
        v = *(const float4*)(src3 + row * DD + k4);
        B1[k4+0][row] = v.x; B1[k4+1][row] = v.y; B1[k4+2][row] = v.z; B1[k4+3][row] = v.w;
        v = *(const float4*)(src4 + row * DD + k4);
        B2[k4+0][row] = v.x; B2[k4+1][row] = v.y; B2[k4+2][row] = v.z; B2[k4+3][row] = v.w;
    }
    __syncthreads();

    int tx = tid & 15, ty = tid >> 4;
    int r0 = ty * 4, c0 = tx * 4;

    float acc[4][4] = {};
    #pragma unroll
    for (int k = 0; k < DD; k++) {
        float4 a1 = *(const float4*)&A1[k][r0];
        float4 b1 = *(const float4*)&B1[k][c0];
        float4 a2 = *(const float4*)&A2[k][r0];
        float4 b2 = *(const float4*)&B2[k][c0];
        float a1v[4] = { a1.x, a1.y, a1.z, a1.w };
        float b1v[4] = { b1.x, b1.y, b1.z, b1.w };
        float a2v[4] = { a2.x, a2.y, a2.z, a2.w };
        float b2v[4] = { b2.x, b2.y, b2.z, b2.w };
        #pragma unroll
        for (int i = 0; i < 4; i++)
            #pragma unroll
            for (int j = 0; j < 4; j++) {
                acc[i][j] = fmaf(a1v[i],  b1v[j], acc[i][j]);
                acc[i][j] = fmaf(-a2v[i], b2v[j], acc[i][j]);
            }
    }

    float t[4][4];
    #pragma unroll
    for (int i = 0; i < 4; i++)
        #pragma unroll
        for (int j = 0; j < 4; j++)
            t[i][j] = fast_tanh(acc[i][j]);

    float* obase = out + (size_t)b * S2;
    #pragma unroll
    for (int i = 0; i < 4; i++) {
        float4 v = { f_out(t[i][0]), f_out(t[i][1]), f_out(t[i][2]), f_out(t[i][3]) };
        *(float4*)(obase + (size_t)(ti * 64 + r0 + i) * NTOT + tj * 64 + c0) = v;
    }
    if (ti != tj) {
        #pragma unroll
        for (int j = 0; j < 4; j++) {
            float4 v = { f_out(-t[0][j]), f_out(-t[1][j]), f_out(-t[2][j]), f_out(-t[3][j]) };
            *(float4*)(obase + (size_t)(tj * 64 + c0 + j) * NTOT + ti * 64 + r0) = v;
        }
    }
}

// ---------------------------------------------------------------------------
// st block: out[b, n, 2048+t] = f(s_st1[b,n] + s_st2[b,t])   (bias folded)
// ---------------------------------------------------------------------------
__global__ void st_kernel(const float* __restrict__ ws, float* __restrict__ out) {
    const float* s_st1 = ws + WS_SST1;
    const float* s_st2 = ws + WS_SST2;
    int idx = blockIdx.x * 256 + threadIdx.x;          // 4*2048*72 = 589824
    if (idx >= BATCH * NS * (NT / 4)) return;
    int t4  = idx % (NT / 4);
    int row = idx / (NT / 4);                          // b*2048 + n
    int b   = row >> 11;
    int n   = row & (NS - 1);
    float  s1 = s_st1[row];
    float4 s2 = *(const float4*)(s_st2 + b * NT + t4 * 4);
    float4 v  = { f_out(s1 + s2.x), f_out(s1 + s2.y), f_out(s1 + s2.z), f_out(s1 + s2.w) };
    *(float4*)(out + (size_t)b * S2 + (size_t)n * NTOT + NS + t4 * 4) = v;
}

// ---------------------------------------------------------------------------
// ts block: out[b, 2048+t, n] = f(s_ts1[b,t] + s_ts2[b,n])   (bias folded)
// ---------------------------------------------------------------------------
__global__ void ts_kernel(const float* __restrict__ ws, float* __restrict__ out) {
    const float* s_ts1 = ws + WS_STS1;
    const float* s_ts2 = ws + WS_STS2;
    int idx = blockIdx.x * 256 + threadIdx.x;          // 4*288*512 = 589824
    if (idx >= BATCH * NT * (NS / 4)) return;
    int n4  = idx & 511;
    int row = idx >> 9;                                // b*288 + t
    int b   = row / NT;
    int t   = row - b * NT;
    float  s1 = s_ts1[row];
    float4 s2 = *(const float4*)(s_ts2 + b * NS + n4 * 4);
    float4 v  = { f_out(s1 + s2.x), f_out(s1 + s2.y), f_out(s1 + s2.z), f_out(s1 + s2.w) };
    *(float4*)(out + (size_t)b * S2 + (size_t)(NS + t) * NTOT + n4 * 4) = v;
}

// ---------------------------------------------------------------------------
// tt block: out[b, 2048+i, 2048+j] = (j>=i) ? f(T_i . T_j) : 0
// ---------------------------------------------------------------------------
__global__ void tt_kernel(const float* __restrict__ T, float* __restrict__ out) {
    int idx = blockIdx.x * 256 + threadIdx.x;          // 4*288*288 = 331776
    if (idx >= BATCH * NT * NT) return;
    int j   = idx % NT;
    int rem = idx / NT;
    int i   = rem % NT;
    int b   = rem / NT;
    float o = 0.f;
    if (j >= i) {
        const float4* ri = (const float4*)(T + (b * NT + i) * DD);
        const float4* rj = (const float4*)(T + (b * NT + j) * DD);
        float acc = 0.f;
        #pragma unroll
        for (int q = 0; q < 8; q++) {
            float4 a = ri[q], c = rj[q];
            acc = fmaf(a.x, c.x, acc); acc = fmaf(a.y, c.y, acc);
            acc = fmaf(a.z, c.z, acc); acc = fmaf(a.w, c.w, acc);
        }
        o = f_out(acc);
    }
    out[(size_t)b * S2 + (size_t)(NS + i) * NTOT + NS + j] = o;
}

extern "C" void kernel_launch(void* const* d_in, const int* in_sizes, int n_in,
                              void* d_out, int out_size, void* d_ws, size_t ws_size,
                              hipStream_t stream) {
    const float* S    = (const float*)d_in[0];
    const float* T    = (const float*)d_in[1];
    const float* W1   = (const float*)d_in[2];
    const float* W2   = (const float*)d_in[3];
    const float* w_st = (const float*)d_in[4];
    const float* b_st = (const float*)d_in[5];
    const float* w_ts = (const float*)d_in[6];
    const float* b_ts = (const float*)d_in[7];
    float* out = (float*)d_out;
    float* ws  = (float*)d_ws;

    precompute_kernel<<<37, 256, 0, stream>>>(S, T, W1, W2, w_st, b_st, w_ts, b_ts, ws);
    ss_kernel<<<dim3(32, 32, BATCH), 256, 0, stream>>>(ws, ws + WS_NV2, out);
    st_kernel<<<2304, 256, 0, stream>>>(ws, out);
    ts_kernel<<<2304, 256, 0, stream>>>(ws, out);
    tt_kernel<<<1296, 256, 0, stream>>>((const float*)d_in[1], out);
}

// Round 2
// 153.685 us; speedup vs baseline: 1.0549x; 1.0549x over previous
//
#include <hip/hip_runtime.h>

#define NTOT 2336
#define NS   2048
#define NT   288
#define DD   32
#define BATCH 4
#define S2   ((size_t)NTOT * NTOT)
#define LDSS 68   // LDS row stride (floats): 64 + 4 pad, keeps 16B alignment, breaks bank conflicts

// ws layout (floats):
//   nv1   : [4][2048][32] @ 0
//   nv2   : [4][2048][32] @ 262144
//   s_st1 : [4][2048]     @ 524288   (includes +b_st)
//   s_st2 : [4][288]      @ 532480
//   s_ts1 : [4][288]      @ 533632   (includes +b_ts)
//   s_ts2 : [4][2048]     @ 534784
// total 542976 floats = 2.17 MB
#define WS_NV2   (BATCH * NS * DD)
#define WS_SST1  (2 * BATCH * NS * DD)
#define WS_SST2  (WS_SST1 + BATCH * NS)
#define WS_STS1  (WS_SST2 + BATCH * NT)
#define WS_STS2  (WS_STS1 + BATCH * NT)

__device__ __forceinline__ float fast_tanh(float x) {
    float e = __expf(2.0f * x);
    return 1.0f - 2.0f * __builtin_amdgcn_rcpf(e + 1.0f);
}
// tanh(relu(x))
__device__ __forceinline__ float f_out(float x) {
    return fast_tanh(fmaxf(x, 0.0f));
}

// ---------------------------------------------------------------------------
// Precompute: nv1/nv2 (tanh(3 * S @ W^T)) and the four pair-linear vectors.
// R2 fix: fully unrolled d-loop, outputs consumed into float4 stores
// immediately -> no dynamically-indexed private arrays -> no scratch spill.
// ---------------------------------------------------------------------------
__global__ void precompute_kernel(const float* __restrict__ S,
                                  const float* __restrict__ T,
                                  const float* __restrict__ W1,
                                  const float* __restrict__ W2,
                                  const float* __restrict__ w_st,
                                  const float* __restrict__ b_st,
                                  const float* __restrict__ w_ts,
                                  const float* __restrict__ b_ts,
                                  float* __restrict__ ws) {
    __shared__ float sW1[DD * DD];
    __shared__ float sW2[DD * DD];
    __shared__ float swst[2 * DD];
    __shared__ float swts[2 * DD];
    int tid = threadIdx.x;
    for (int i = tid; i < DD * DD; i += 256) { sW1[i] = W1[i]; sW2[i] = W2[i]; }
    if (tid < 2 * DD) { swst[tid] = w_st[tid]; swts[tid] = w_ts[tid]; }
    __syncthreads();

    float* nv1   = ws;
    float* nv2   = ws + WS_NV2;
    float* s_st1 = ws + WS_SST1;
    float* s_st2 = ws + WS_SST2;
    float* s_ts1 = ws + WS_STS1;
    float* s_ts2 = ws + WS_STS2;

    int idx = blockIdx.x * 256 + tid;
    if (idx < BATCH * NS) {
        // one spatial row: nv1 row, nv2 row, s_st1, s_ts2
        const float* row = S + idx * DD;
        float r[DD];
        #pragma unroll
        for (int q = 0; q < 8; q++) {
            float4 v = ((const float4*)row)[q];
            r[q * 4 + 0] = v.x; r[q * 4 + 1] = v.y;
            r[q * 4 + 2] = v.z; r[q * 4 + 3] = v.w;
        }
        #pragma unroll
        for (int q = 0; q < 8; q++) {
            float o1[4], o2[4];
            #pragma unroll
            for (int p = 0; p < 4; p++) {
                int d = q * 4 + p;
                float a1 = 0.f, a2 = 0.f;
                #pragma unroll
                for (int k = 0; k < DD; k++) {
                    a1 = fmaf(r[k], sW1[d * DD + k], a1);
                    a2 = fmaf(r[k], sW2[d * DD + k], a2);
                }
                o1[p] = fast_tanh(3.0f * a1);
                o2[p] = fast_tanh(3.0f * a2);
            }
            float4 v1 = { o1[0], o1[1], o1[2], o1[3] };
            float4 v2 = { o2[0], o2[1], o2[2], o2[3] };
            ((float4*)(nv1 + idx * DD))[q] = v1;
            ((float4*)(nv2 + idx * DD))[q] = v2;
        }
        float d1 = 0.f, d2 = 0.f;
        #pragma unroll
        for (int k = 0; k < DD; k++) {
            d1 = fmaf(r[k], swst[k], d1);
            d2 = fmaf(r[k], swts[DD + k], d2);
        }
        s_st1[idx] = d1 + b_st[0];
        s_ts2[idx] = d2;
    } else if (idx < BATCH * NS + BATCH * NT) {
        int t = idx - BATCH * NS;
        const float* row = T + t * DD;
        float r[DD];
        #pragma unroll
        for (int q = 0; q < 8; q++) {
            float4 v = ((const float4*)row)[q];
            r[q * 4 + 0] = v.x; r[q * 4 + 1] = v.y;
            r[q * 4 + 2] = v.z; r[q * 4 + 3] = v.w;
        }
        float d1 = 0.f, d2 = 0.f;
        #pragma unroll
        for (int k = 0; k < DD; k++) {
            d1 = fmaf(r[k], swst[DD + k], d1);
            d2 = fmaf(r[k], swts[k], d2);
        }
        s_st2[t] = d1;
        s_ts1[t] = d2 + b_ts[0];
    }
}

// ---------------------------------------------------------------------------
// ss block: x = nv1_i . nv2_j - nv2_i . nv1_j  (== m - m^T without transpose)
// out[i,j] = tanh(relu(tanh(x)));  mirror out[j,i] = tanh(relu(-tanh(x)))
// Upper-triangular tile pairs only; 64x64 tiles, 16x16 threads x 4x4 micro.
// LDS transposed [k][row] so inner-loop reads are ds_read_b128.
// ---------------------------------------------------------------------------
__global__ __launch_bounds__(256, 4) void ss_kernel(const float* __restrict__ nv1,
                                                    const float* __restrict__ nv2,
                                                    float* __restrict__ out) {
    int ti = blockIdx.x, tj = blockIdx.y, b = blockIdx.z;
    if (tj < ti) return;

    __shared__ __align__(16) float A1[DD][LDSS];  // nv1 rows of tile ti
    __shared__ __align__(16) float A2[DD][LDSS];  // nv2 rows of tile ti
    __shared__ __align__(16) float B1[DD][LDSS];  // nv2 rows of tile tj
    __shared__ __align__(16) float B2[DD][LDSS];  // nv1 rows of tile tj

    int tid = threadIdx.x;
    const float* src1 = nv1 + ((size_t)b * NS + ti * 64) * DD;
    const float* src2 = nv2 + ((size_t)b * NS + ti * 64) * DD;
    const float* src3 = nv2 + ((size_t)b * NS + tj * 64) * DD;
    const float* src4 = nv1 + ((size_t)b * NS + tj * 64) * DD;

    #pragma unroll
    for (int rep = 0; rep < 2; rep++) {
        int q   = rep * 256 + tid;
        int row = q >> 3;
        int k4  = (q & 7) * 4;
        float4 v;
        v = *(const float4*)(src1 + row * DD + k4);
        A1[k4+0][row] = v.x; A1[k4+1][row] = v.y; A1[k4+2][row] = v.z; A1[k4+3][row] = v.w;
        v = *(const float4*)(src2 + row * DD + k4);
        A2[k4+0][row] = v.x; A2[k4+1][row] = v.y; A2[k4+2][row] = v.z; A2[k4+3][row] = v.w;
        v = *(const float4*)(src3 + row * DD + k4);
        B1[k4+0][row] = v.x; B1[k4+1][row] = v.y; B1[k4+2][row] = v.z; B1[k4+3][row] = v.w;
        v = *(const float4*)(src4 + row * DD + k4);
        B2[k4+0][row] = v.x; B2[k4+1][row] = v.y; B2[k4+2][row] = v.z; B2[k4+3][row] = v.w;
    }
    __syncthreads();

    int tx = tid & 15, ty = tid >> 4;
    int r0 = ty * 4, c0 = tx * 4;

    float acc[4][4] = {};
    #pragma unroll
    for (int k = 0; k < DD; k++) {
        float4 a1 = *(const float4*)&A1[k][r0];
        float4 b1 = *(const float4*)&B1[k][c0];
        float4 a2 = *(const float4*)&A2[k][r0];
        float4 b2 = *(const float4*)&B2[k][c0];
        float a1v[4] = { a1.x, a1.y, a1.z, a1.w };
        float b1v[4] = { b1.x, b1.y, b1.z, b1.w };
        float a2v[4] = { a2.x, a2.y, a2.z, a2.w };
        float b2v[4] = { b2.x, b2.y, b2.z, b2.w };
        #pragma unroll
        for (int i = 0; i < 4; i++)
            #pragma unroll
            for (int j = 0; j < 4; j++) {
                acc[i][j] = fmaf(a1v[i],  b1v[j], acc[i][j]);
                acc[i][j] = fmaf(-a2v[i], b2v[j], acc[i][j]);
            }
    }

    float t[4][4];
    #pragma unroll
    for (int i = 0; i < 4; i++)
        #pragma unroll
        for (int j = 0; j < 4; j++)
            t[i][j] = fast_tanh(acc[i][j]);

    float* obase = out + (size_t)b * S2;
    #pragma unroll
    for (int i = 0; i < 4; i++) {
        float4 v = { f_out(t[i][0]), f_out(t[i][1]), f_out(t[i][2]), f_out(t[i][3]) };
        *(float4*)(obase + (size_t)(ti * 64 + r0 + i) * NTOT + tj * 64 + c0) = v;
    }
    if (ti != tj) {
        #pragma unroll
        for (int j = 0; j < 4; j++) {
            float4 v = { f_out(-t[0][j]), f_out(-t[1][j]), f_out(-t[2][j]), f_out(-t[3][j]) };
            *(float4*)(obase + (size_t)(tj * 64 + c0 + j) * NTOT + ti * 64 + r0) = v;
        }
    }
}

// ---------------------------------------------------------------------------
// st block: out[b, n, 2048+t] = f(s_st1[b,n] + s_st2[b,t])   (bias folded)
// ---------------------------------------------------------------------------
__global__ void st_kernel(const float* __restrict__ ws, float* __restrict__ out) {
    const float* s_st1 = ws + WS_SST1;
    const float* s_st2 = ws + WS_SST2;
    int idx = blockIdx.x * 256 + threadIdx.x;          // 4*2048*72 = 589824
    if (idx >= BATCH * NS * (NT / 4)) return;
    int t4  = idx % (NT / 4);
    int row = idx / (NT / 4);                          // b*2048 + n
    int b   = row >> 11;
    int n   = row & (NS - 1);
    float  s1 = s_st1[row];
    float4 s2 = *(const float4*)(s_st2 + b * NT + t4 * 4);
    float4 v  = { f_out(s1 + s2.x), f_out(s1 + s2.y), f_out(s1 + s2.z), f_out(s1 + s2.w) };
    *(float4*)(out + (size_t)b * S2 + (size_t)n * NTOT + NS + t4 * 4) = v;
}

// ---------------------------------------------------------------------------
// ts block: out[b, 2048+t, n] = f(s_ts1[b,t] + s_ts2[b,n])   (bias folded)
// ---------------------------------------------------------------------------
__global__ void ts_kernel(const float* __restrict__ ws, float* __restrict__ out) {
    const float* s_ts1 = ws + WS_STS1;
    const float* s_ts2 = ws + WS_STS2;
    int idx = blockIdx.x * 256 + threadIdx.x;          // 4*288*512 = 589824
    if (idx >= BATCH * NT * (NS / 4)) return;
    int n4  = idx & 511;
    int row = idx >> 9;                                // b*288 + t
    int b   = row / NT;
    int t   = row - b * NT;
    float  s1 = s_ts1[row];
    float4 s2 = *(const float4*)(s_ts2 + b * NS + n4 * 4);
    float4 v  = { f_out(s1 + s2.x), f_out(s1 + s2.y), f_out(s1 + s2.z), f_out(s1 + s2.w) };
    *(float4*)(out + (size_t)b * S2 + (size_t)(NS + t) * NTOT + n4 * 4) = v;
}

// ---------------------------------------------------------------------------
// tt block: out[b, 2048+i, 2048+j] = (j>=i) ? f(T_i . T_j) : 0
// ---------------------------------------------------------------------------
__global__ void tt_kernel(const float* __restrict__ T, float* __restrict__ out) {
    int idx = blockIdx.x * 256 + threadIdx.x;          // 4*288*288 = 331776
    if (idx >= BATCH * NT * NT) return;
    int j   = idx % NT;
    int rem = idx / NT;
    int i   = rem % NT;
    int b   = rem / NT;
    float o = 0.f;
    if (j >= i) {
        const float4* ri = (const float4*)(T + (b * NT + i) * DD);
        const float4* rj = (const float4*)(T + (b * NT + j) * DD);
        float acc = 0.f;
        #pragma unroll
        for (int q = 0; q < 8; q++) {
            float4 a = ri[q], c = rj[q];
            acc = fmaf(a.x, c.x, acc); acc = fmaf(a.y, c.y, acc);
            acc = fmaf(a.z, c.z, acc); acc = fmaf(a.w, c.w, acc);
        }
        o = f_out(acc);
    }
    out[(size_t)b * S2 + (size_t)(NS + i) * NTOT + NS + j] = o;
}

extern "C" void kernel_launch(void* const* d_in, const int* in_sizes, int n_in,
                              void* d_out, int out_size, void* d_ws, size_t ws_size,
                              hipStream_t stream) {
    const float* S    = (const float*)d_in[0];
    const float* T    = (const float*)d_in[1];
    const float* W1   = (const float*)d_in[2];
    const float* W2   = (const float*)d_in[3];
    const float* w_st = (const float*)d_in[4];
    const float* b_st = (const float*)d_in[5];
    const float* w_ts = (const float*)d_in[6];
    const float* b_ts = (const float*)d_in[7];
    float* out = (float*)d_out;
    float* ws  = (float*)d_ws;

    precompute_kernel<<<37, 256, 0, stream>>>(S, T, W1, W2, w_st, b_st, w_ts, b_ts, ws);
    ss_kernel<<<dim3(32, 32, BATCH), 256, 0, stream>>>(ws, ws + WS_NV2, out);
    st_kernel<<<2304, 256, 0, stream>>>(ws, out);
    ts_kernel<<<2304, 256, 0, stream>>>(ws, out);
    tt_kernel<<<1296, 256, 0, stream>>>((const float*)d_in[1], out);
}

// Round 3
// 138.687 us; speedup vs baseline: 1.1690x; 1.1081x over previous
//
#include <hip/hip_runtime.h>

#define NTOT 2336
#define NS   2048
#define NT   288
#define DD   32
#define BATCH 4
#define S2   ((size_t)NTOT * NTOT)

// ws layout (floats). nv1/nv2 are TRANSPOSED: [b][d][n] (d-major) so the ss
// staging loads are coalesced rows and LDS stores are ds_write_b128.
//   nv1T  : [4][32][2048] @ 0
//   nv2T  : [4][32][2048] @ 262144
//   s_st1 : [4][2048]     @ 524288   (includes +b_st)
//   s_st2 : [4][288]      @ 532480
//   s_ts1 : [4][288]      @ 533632   (includes +b_ts)
//   s_ts2 : [4][2048]     @ 534784
#define WS_NV2   (BATCH * NS * DD)
#define WS_SST1  (2 * BATCH * NS * DD)
#define WS_SST2  (WS_SST1 + BATCH * NS)
#define WS_STS1  (WS_SST2 + BATCH * NT)
#define WS_STS2  (WS_STS1 + BATCH * NT)

#define TILE   128
#define NTILE  (NS / TILE)                  // 16
#define NPAIR  (NTILE * (NTILE + 1) / 2)    // 136
#define SS_BLOCKS (NPAIR * BATCH)           // 544
#define ST_BLOCKS 2304                      // 4*2048*72 / 256
#define TS_BLOCKS 2304                      // 4*288*512 / 256
#define TT_BLOCKS 1296                      // 4*288*288 / 256
#define GRID_BLOCKS (SS_BLOCKS + ST_BLOCKS + TS_BLOCKS + TT_BLOCKS)
#define LDST 136   // LDS col stride: 128+8 -> staging b128 stores & frag reads are <=2-way (free)

__device__ __forceinline__ float fast_tanh(float x) {
    float e = __expf(2.0f * x);
    return 1.0f - 2.0f * __builtin_amdgcn_rcpf(e + 1.0f);
}
// tanh(relu(x))
__device__ __forceinline__ float f_out(float x) {
    return fast_tanh(fmaxf(x, 0.0f));
}

// ---------------------------------------------------------------------------
// Precompute: nv1T/nv2T = tanh(3 * S @ W^T) stored [b][d][n], plus the four
// pair-linear vectors. Fully unrolled -> no scratch. Transposed stores are
// coalesced (consecutive lanes = consecutive n).
// ---------------------------------------------------------------------------
__global__ void precompute_kernel(const float* __restrict__ S,
                                  const float* __restrict__ T,
                                  const float* __restrict__ W1,
                                  const float* __restrict__ W2,
                                  const float* __restrict__ w_st,
                                  const float* __restrict__ b_st,
                                  const float* __restrict__ w_ts,
                                  const float* __restrict__ b_ts,
                                  float* __restrict__ ws) {
    __shared__ float sW1[DD * DD];
    __shared__ float sW2[DD * DD];
    __shared__ float swst[2 * DD];
    __shared__ float swts[2 * DD];
    int tid = threadIdx.x;
    for (int i = tid; i < DD * DD; i += 256) { sW1[i] = W1[i]; sW2[i] = W2[i]; }
    if (tid < 2 * DD) { swst[tid] = w_st[tid]; swts[tid] = w_ts[tid]; }
    __syncthreads();

    float* nv1T  = ws;
    float* nv2T  = ws + WS_NV2;
    float* s_st1 = ws + WS_SST1;
    float* s_st2 = ws + WS_SST2;
    float* s_ts1 = ws + WS_STS1;
    float* s_ts2 = ws + WS_STS2;

    int idx = blockIdx.x * 256 + tid;
    if (idx < BATCH * NS) {
        int b = idx >> 11, n = idx & (NS - 1);
        const float* row = S + idx * DD;
        float r[DD];
        #pragma unroll
        for (int q = 0; q < 8; q++) {
            float4 v = ((const float4*)row)[q];
            r[q * 4 + 0] = v.x; r[q * 4 + 1] = v.y;
            r[q * 4 + 2] = v.z; r[q * 4 + 3] = v.w;
        }
        size_t base = (size_t)b * DD * NS + n;
        #pragma unroll
        for (int d = 0; d < DD; d++) {
            float a1 = 0.f, a2 = 0.f;
            #pragma unroll
            for (int k = 0; k < DD; k++) {
                a1 = fmaf(r[k], sW1[d * DD + k], a1);
                a2 = fmaf(r[k], sW2[d * DD + k], a2);
            }
            nv1T[base + (size_t)d * NS] = fast_tanh(3.0f * a1);
            nv2T[base + (size_t)d * NS] = fast_tanh(3.0f * a2);
        }
        float d1 = 0.f, d2 = 0.f;
        #pragma unroll
        for (int k = 0; k < DD; k++) {
            d1 = fmaf(r[k], swst[k], d1);
            d2 = fmaf(r[k], swts[DD + k], d2);
        }
        s_st1[idx] = d1 + b_st[0];
        s_ts2[idx] = d2;
    } else if (idx < BATCH * NS + BATCH * NT) {
        int t = idx - BATCH * NS;
        const float* row = T + t * DD;
        float r[DD];
        #pragma unroll
        for (int q = 0; q < 8; q++) {
            float4 v = ((const float4*)row)[q];
            r[q * 4 + 0] = v.x; r[q * 4 + 1] = v.y;
            r[q * 4 + 2] = v.z; r[q * 4 + 3] = v.w;
        }
        float d1 = 0.f, d2 = 0.f;
        #pragma unroll
        for (int k = 0; k < DD; k++) {
            d1 = fmaf(r[k], swst[DD + k], d1);
            d2 = fmaf(r[k], swts[k], d2);
        }
        s_st2[t] = d1;
        s_ts1[t] = d2 + b_ts[0];
    }
}

// ---------------------------------------------------------------------------
// Mega kernel: one dispatch covers ss + st + ts + tt by blockIdx range.
// ss blocks first (longest work) so they schedule earliest; st/ts/tt blocks
// fill in behind and overlap their HBM writes with ss compute.
// ---------------------------------------------------------------------------
__global__ __launch_bounds__(256) void mega_kernel(const float* __restrict__ ws,
                                                   const float* __restrict__ T,
                                                   float* __restrict__ out) {
    __shared__ __align__(16) float sA1[16][LDST];
    __shared__ __align__(16) float sA2[16][LDST];
    __shared__ __align__(16) float sB1[16][LDST];
    __shared__ __align__(16) float sB2[16][LDST];

    int blk = blockIdx.x;
    int tid = threadIdx.x;

    if (blk < SS_BLOCKS) {
        // ---- ss: 128x128 tile pair (ti, tj) upper-tri, 8x8 micro per thread
        int b = blk & 3;
        int p = blk >> 2;
        int ti = 0;
        while (p >= NTILE - ti) { p -= NTILE - ti; ti++; }
        int tj = ti + p;

        const float* nv1T = ws + (size_t)b * DD * NS;
        const float* nv2T = ws + WS_NV2 + (size_t)b * DD * NS;

        int tx = tid & 15, ty = tid >> 4;
        float acc[8][8] = {};

        #pragma unroll
        for (int ph = 0; ph < 2; ph++) {
            if (ph) __syncthreads();
            #pragma unroll
            for (int it = 0; it < 2; it++) {
                int idx = it * 256 + tid;            // 0..511
                int k   = idx >> 5;                  // 0..15
                int c4  = (idx & 31) * 4;            // 0..124
                const float* g = nv1T + (size_t)(ph * 16 + k) * NS;
                const float* h = nv2T + (size_t)(ph * 16 + k) * NS;
                *(float4*)&sA1[k][c4] = *(const float4*)(g + ti * TILE + c4);
                *(float4*)&sA2[k][c4] = *(const float4*)(h + ti * TILE + c4);
                *(float4*)&sB1[k][c4] = *(const float4*)(h + tj * TILE + c4);
                *(float4*)&sB2[k][c4] = *(const float4*)(g + tj * TILE + c4);
            }
            __syncthreads();
            #pragma unroll
            for (int k = 0; k < 16; k++) {
                float4 a1l = *(const float4*)&sA1[k][ty * 4];
                float4 a1h = *(const float4*)&sA1[k][64 + ty * 4];
                float4 a2l = *(const float4*)&sA2[k][ty * 4];
                float4 a2h = *(const float4*)&sA2[k][64 + ty * 4];
                float4 b1l = *(const float4*)&sB1[k][tx * 4];
                float4 b1h = *(const float4*)&sB1[k][64 + tx * 4];
                float4 b2l = *(const float4*)&sB2[k][tx * 4];
                float4 b2h = *(const float4*)&sB2[k][64 + tx * 4];
                float av1[8] = { a1l.x,a1l.y,a1l.z,a1l.w, a1h.x,a1h.y,a1h.z,a1h.w };
                float av2[8] = { a2l.x,a2l.y,a2l.z,a2l.w, a2h.x,a2h.y,a2h.z,a2h.w };
                float bv1[8] = { b1l.x,b1l.y,b1l.z,b1l.w, b1h.x,b1h.y,b1h.z,b1h.w };
                float bv2[8] = { b2l.x,b2l.y,b2l.z,b2l.w, b2h.x,b2h.y,b2h.z,b2h.w };
                #pragma unroll
                for (int i = 0; i < 8; i++)
                    #pragma unroll
                    for (int j = 0; j < 8; j++) {
                        acc[i][j] = fmaf(av1[i],  bv1[j], acc[i][j]);
                        acc[i][j] = fmaf(-av2[i], bv2[j], acc[i][j]);
                    }
            }
        }

        // epilogue: t = tanh(x); out[i,j] = f(t), mirror out[j,i] = f(-t)
        #pragma unroll
        for (int i = 0; i < 8; i++)
            #pragma unroll
            for (int j = 0; j < 8; j++)
                acc[i][j] = fast_tanh(acc[i][j]);

        float* obase = out + (size_t)b * S2;
        #pragma unroll
        for (int i = 0; i < 8; i++) {
            int r = ti * TILE + ((i < 4) ? (ty * 4 + i) : (60 + ty * 4 + i));
            float4 v0 = { f_out(acc[i][0]), f_out(acc[i][1]), f_out(acc[i][2]), f_out(acc[i][3]) };
            float4 v1 = { f_out(acc[i][4]), f_out(acc[i][5]), f_out(acc[i][6]), f_out(acc[i][7]) };
            *(float4*)(obase + (size_t)r * NTOT + tj * TILE + tx * 4)      = v0;
            *(float4*)(obase + (size_t)r * NTOT + tj * TILE + 64 + tx * 4) = v1;
        }
        if (ti != tj) {
            #pragma unroll
            for (int j = 0; j < 8; j++) {
                int r = tj * TILE + ((j < 4) ? (tx * 4 + j) : (60 + tx * 4 + j));
                float4 v0 = { f_out(-acc[0][j]), f_out(-acc[1][j]), f_out(-acc[2][j]), f_out(-acc[3][j]) };
                float4 v1 = { f_out(-acc[4][j]), f_out(-acc[5][j]), f_out(-acc[6][j]), f_out(-acc[7][j]) };
                *(float4*)(obase + (size_t)r * NTOT + ti * TILE + ty * 4)      = v0;
                *(float4*)(obase + (size_t)r * NTOT + ti * TILE + 64 + ty * 4) = v1;
            }
        }
    } else if (blk < SS_BLOCKS + ST_BLOCKS) {
        // ---- st: out[b, n, 2048+t] = f(s_st1[b,n] + s_st2[b,t])
        const float* s_st1 = ws + WS_SST1;
        const float* s_st2 = ws + WS_SST2;
        int idx = (blk - SS_BLOCKS) * 256 + tid;       // < 589824
        int t4  = idx % (NT / 4);
        int row = idx / (NT / 4);                      // b*2048 + n
        int b   = row >> 11;
        int n   = row & (NS - 1);
        float  s1 = s_st1[row];
        float4 s2 = *(const float4*)(s_st2 + b * NT + t4 * 4);
        float4 v  = { f_out(s1 + s2.x), f_out(s1 + s2.y), f_out(s1 + s2.z), f_out(s1 + s2.w) };
        *(float4*)(out + (size_t)b * S2 + (size_t)n * NTOT + NS + t4 * 4) = v;
    } else if (blk < SS_BLOCKS + ST_BLOCKS + TS_BLOCKS) {
        // ---- ts: out[b, 2048+t, n] = f(s_ts1[b,t] + s_ts2[b,n])
        const float* s_ts1 = ws + WS_STS1;
        const float* s_ts2 = ws + WS_STS2;
        int idx = (blk - SS_BLOCKS - ST_BLOCKS) * 256 + tid;   // < 589824
        int n4  = idx & 511;
        int row = idx >> 9;                            // b*288 + t
        int b   = row / NT;
        int t   = row - b * NT;
        float  s1 = s_ts1[row];
        float4 s2 = *(const float4*)(s_ts2 + b * NS + n4 * 4);
        float4 v  = { f_out(s1 + s2.x), f_out(s1 + s2.y), f_out(s1 + s2.z), f_out(s1 + s2.w) };
        *(float4*)(out + (size_t)b * S2 + (size_t)(NS + t) * NTOT + n4 * 4) = v;
    } else {
        // ---- tt: out[b, 2048+i, 2048+j] = (j>=i) ? f(T_i . T_j) : 0
        int idx = (blk - SS_BLOCKS - ST_BLOCKS - TS_BLOCKS) * 256 + tid;  // < 331776
        int j   = idx % NT;
        int rem = idx / NT;
        int i   = rem % NT;
        int b   = rem / NT;
        float o = 0.f;
        if (j >= i) {
            const float4* ri = (const float4*)(T + (b * NT + i) * DD);
            const float4* rj = (const float4*)(T + (b * NT + j) * DD);
            float acc = 0.f;
            #pragma unroll
            for (int q = 0; q < 8; q++) {
                float4 a = ri[q], c = rj[q];
                acc = fmaf(a.x, c.x, acc); acc = fmaf(a.y, c.y, acc);
                acc = fmaf(a.z, c.z, acc); acc = fmaf(a.w, c.w, acc);
            }
            o = f_out(acc);
        }
        out[(size_t)b * S2 + (size_t)(NS + i) * NTOT + NS + j] = o;
    }
}

extern "C" void kernel_launch(void* const* d_in, const int* in_sizes, int n_in,
                              void* d_out, int out_size, void* d_ws, size_t ws_size,
                              hipStream_t stream) {
    const float* S    = (const float*)d_in[0];
    const float* T    = (const float*)d_in[1];
    const float* W1   = (const float*)d_in[2];
    const float* W2   = (const float*)d_in[3];
    const float* w_st = (const float*)d_in[4];
    const float* b_st = (const float*)d_in[5];
    const float* w_ts = (const float*)d_in[6];
    const float* b_ts = (const float*)d_in[7];
    float* out = (float*)d_out;
    float* ws  = (float*)d_ws;

    precompute_kernel<<<37, 256, 0, stream>>>(S, T, W1, W2, w_st, b_st, w_ts, b_ts, ws);
    mega_kernel<<<GRID_BLOCKS, 256, 0, stream>>>(ws, T, out);
}

// Round 4
// 132.455 us; speedup vs baseline: 1.2240x; 1.0471x over previous
//
#include <hip/hip_runtime.h>

#define NTOT 2336
#define NS   2048
#define NT   288
#define DD   32
#define KK   16          // k-pairs (half2 along k)
#define BATCH 4
#define S2   ((size_t)NTOT * NTOT)

typedef _Float16 half2_t __attribute__((ext_vector_type(2)));

// ws layout (floats). nv1/nv2 stored TRANSPOSED and f16-PACKED: [b][kk][n],
// each float is a half2 holding (k=2kk, k=2kk+1). Coalesced in n.
//   nv1h  : [4][16][2048] @ 0        (131072 floats)
//   nv2h  : [4][16][2048] @ 131072
//   s_st1 : [4][2048]     @ 262144   (includes +b_st)
//   s_st2 : [4][288]      @ 270336
//   s_ts1 : [4][288]      @ 271488   (includes +b_ts)
//   s_ts2 : [4][2048]     @ 272640
#define WS_NV2H  (BATCH * KK * NS)
#define WS_SST1  (2 * BATCH * KK * NS)
#define WS_SST2  (WS_SST1 + BATCH * NS)
#define WS_STS1  (WS_SST2 + BATCH * NT)
#define WS_STS2  (WS_STS1 + BATCH * NT)

#define TILE   128
#define NTILE  (NS / TILE)                  // 16
#define NPAIR  (NTILE * (NTILE + 1) / 2)    // 136
#define SS_BLOCKS (NPAIR * BATCH)           // 544
#define ST_BLOCKS 2304
#define TS_BLOCKS 2304
#define TT_BLOCKS 1296
#define GRID_BLOCKS (SS_BLOCKS + ST_BLOCKS + TS_BLOCKS + TT_BLOCKS)
#define LDST 136   // LDS col stride (floats): 128+8

__device__ __forceinline__ float fast_tanh(float x) {
    float e = __expf(2.0f * x);
    return 1.0f - 2.0f * __builtin_amdgcn_rcpf(e + 1.0f);
}
// tanh(relu(x)) for unbounded x (st/ts/tt path)
__device__ __forceinline__ float f_out(float x) {
    return fast_tanh(fmaxf(x, 0.0f));
}
// odd minimax poly for tanh(u), u in [-1,1]; max err ~2.1e-3
__device__ __forceinline__ float poly_tanh01(float t) {
    float t2 = t * t;
    return t * fmaf(t2, fmaf(t2, 0.086330f, -0.324600f), 0.999905f);
}
__device__ __forceinline__ float fdot2(half2_t a, half2_t b, float c) {
#if __has_builtin(__builtin_amdgcn_fdot2)
    return __builtin_amdgcn_fdot2(a, b, c, false);
#else
    return c + (float)a.x * (float)b.x + (float)a.y * (float)b.y;
#endif
}
__device__ __forceinline__ half2_t bc_h2(float f) {
    return __builtin_bit_cast(half2_t, f);
}

// ---------------------------------------------------------------------------
// Precompute: nv1h/nv2h = tanh(3 * S @ W^T) as k-packed half2, [b][kk][n];
// plus the four pair-linear vectors (fp32). Fully unrolled -> no scratch.
// ---------------------------------------------------------------------------
__global__ void precompute_kernel(const float* __restrict__ S,
                                  const float* __restrict__ T,
                                  const float* __restrict__ W1,
                                  const float* __restrict__ W2,
                                  const float* __restrict__ w_st,
                                  const float* __restrict__ b_st,
                                  const float* __restrict__ w_ts,
                                  const float* __restrict__ b_ts,
                                  float* __restrict__ ws) {
    __shared__ float sW1[DD * DD];
    __shared__ float sW2[DD * DD];
    __shared__ float swst[2 * DD];
    __shared__ float swts[2 * DD];
    int tid = threadIdx.x;
    for (int i = tid; i < DD * DD; i += 256) { sW1[i] = W1[i]; sW2[i] = W2[i]; }
    if (tid < 2 * DD) { swst[tid] = w_st[tid]; swts[tid] = w_ts[tid]; }
    __syncthreads();

    float* nv1h  = ws;
    float* nv2h  = ws + WS_NV2H;
    float* s_st1 = ws + WS_SST1;
    float* s_st2 = ws + WS_SST2;
    float* s_ts1 = ws + WS_STS1;
    float* s_ts2 = ws + WS_STS2;

    int idx = blockIdx.x * 256 + tid;
    if (idx < BATCH * NS) {
        int b = idx >> 11, n = idx & (NS - 1);
        const float* row = S + idx * DD;
        float r[DD];
        #pragma unroll
        for (int q = 0; q < 8; q++) {
            float4 v = ((const float4*)row)[q];
            r[q * 4 + 0] = v.x; r[q * 4 + 1] = v.y;
            r[q * 4 + 2] = v.z; r[q * 4 + 3] = v.w;
        }
        float o1[DD], o2[DD];
        #pragma unroll
        for (int d = 0; d < DD; d++) {
            float a1 = 0.f, a2 = 0.f;
            #pragma unroll
            for (int k = 0; k < DD; k++) {
                a1 = fmaf(r[k], sW1[d * DD + k], a1);
                a2 = fmaf(r[k], sW2[d * DD + k], a2);
            }
            o1[d] = fast_tanh(3.0f * a1);
            o2[d] = fast_tanh(3.0f * a2);
        }
        size_t base = (size_t)b * KK * NS + n;
        #pragma unroll
        for (int kk = 0; kk < KK; kk++) {
            half2_t h1 = { (_Float16)o1[2 * kk], (_Float16)o1[2 * kk + 1] };
            half2_t h2 = { (_Float16)o2[2 * kk], (_Float16)o2[2 * kk + 1] };
            nv1h[base + (size_t)kk * NS] = __builtin_bit_cast(float, h1);
            nv2h[base + (size_t)kk * NS] = __builtin_bit_cast(float, h2);
        }
        float d1 = 0.f, d2 = 0.f;
        #pragma unroll
        for (int k = 0; k < DD; k++) {
            d1 = fmaf(r[k], swst[k], d1);
            d2 = fmaf(r[k], swts[DD + k], d2);
        }
        s_st1[idx] = d1 + b_st[0];
        s_ts2[idx] = d2;
    } else if (idx < BATCH * NS + BATCH * NT) {
        int t = idx - BATCH * NS;
        const float* row = T + t * DD;
        float r[DD];
        #pragma unroll
        for (int q = 0; q < 8; q++) {
            float4 v = ((const float4*)row)[q];
            r[q * 4 + 0] = v.x; r[q * 4 + 1] = v.y;
            r[q * 4 + 2] = v.z; r[q * 4 + 3] = v.w;
        }
        float d1 = 0.f, d2 = 0.f;
        #pragma unroll
        for (int k = 0; k < DD; k++) {
            d1 = fmaf(r[k], swst[DD + k], d1);
            d2 = fmaf(r[k], swts[k], d2);
        }
        s_st2[t] = d1;
        s_ts1[t] = d2 + b_ts[0];
    }
}

// ---------------------------------------------------------------------------
// Mega kernel: ss (f16 dot2) + st + ts + tt in one dispatch.
// ---------------------------------------------------------------------------
__global__ __launch_bounds__(256) void mega_kernel(const float* __restrict__ ws,
                                                   const float* __restrict__ T,
                                                   float* __restrict__ out) {
    __shared__ __align__(16) float sA1[KK][LDST];  // nv1 rows (tile ti), half2-packed k
    __shared__ __align__(16) float sA2[KK][LDST];  // -nv2 rows (tile ti)
    __shared__ __align__(16) float sB1[KK][LDST];  // nv2 rows (tile tj)
    __shared__ __align__(16) float sB2[KK][LDST];  // nv1 rows (tile tj)

    int blk = blockIdx.x;
    int tid = threadIdx.x;

    if (blk < SS_BLOCKS) {
        int b = blk & 3;
        int p = blk >> 2;
        int ti = 0;
        while (p >= NTILE - ti) { p -= NTILE - ti; ti++; }
        int tj = ti + p;

        const float* nv1h = ws + (size_t)b * KK * NS;
        const float* nv2h = ws + WS_NV2H + (size_t)b * KK * NS;

        // stage all 32 k (16 half2 slices), one phase
        #pragma unroll
        for (int it = 0; it < 2; it++) {
            int idx = it * 256 + tid;            // 0..511
            int kk  = idx >> 5;                  // 0..15
            int c4  = (idx & 31) * 4;            // 0..124
            const float* g1 = nv1h + (size_t)kk * NS;
            const float* g2 = nv2h + (size_t)kk * NS;
            *(float4*)&sA1[kk][c4] = *(const float4*)(g1 + ti * TILE + c4);
            float4 v = *(const float4*)(g2 + ti * TILE + c4);
            uint4 uv = *(uint4*)&v;
            uv.x ^= 0x80008000u; uv.y ^= 0x80008000u;
            uv.z ^= 0x80008000u; uv.w ^= 0x80008000u;
            *(uint4*)&sA2[kk][c4] = uv;
            *(float4*)&sB1[kk][c4] = *(const float4*)(g2 + tj * TILE + c4);
            *(float4*)&sB2[kk][c4] = *(const float4*)(g1 + tj * TILE + c4);
        }
        __syncthreads();

        int tx = tid & 15, ty = tid >> 4;
        float acc[8][8] = {};

        #pragma unroll 4
        for (int kk = 0; kk < KK; kk++) {
            float4 a1l = *(const float4*)&sA1[kk][ty * 4];
            float4 a1h = *(const float4*)&sA1[kk][64 + ty * 4];
            float4 a2l = *(const float4*)&sA2[kk][ty * 4];
            float4 a2h = *(const float4*)&sA2[kk][64 + ty * 4];
            float4 b1l = *(const float4*)&sB1[kk][tx * 4];
            float4 b1h = *(const float4*)&sB1[kk][64 + tx * 4];
            float4 b2l = *(const float4*)&sB2[kk][tx * 4];
            float4 b2h = *(const float4*)&sB2[kk][64 + tx * 4];
            half2_t av1[8] = { bc_h2(a1l.x), bc_h2(a1l.y), bc_h2(a1l.z), bc_h2(a1l.w),
                               bc_h2(a1h.x), bc_h2(a1h.y), bc_h2(a1h.z), bc_h2(a1h.w) };
            half2_t av2[8] = { bc_h2(a2l.x), bc_h2(a2l.y), bc_h2(a2l.z), bc_h2(a2l.w),
                               bc_h2(a2h.x), bc_h2(a2h.y), bc_h2(a2h.z), bc_h2(a2h.w) };
            half2_t bv1[8] = { bc_h2(b1l.x), bc_h2(b1l.y), bc_h2(b1l.z), bc_h2(b1l.w),
                               bc_h2(b1h.x), bc_h2(b1h.y), bc_h2(b1h.z), bc_h2(b1h.w) };
            half2_t bv2[8] = { bc_h2(b2l.x), bc_h2(b2l.y), bc_h2(b2l.z), bc_h2(b2l.w),
                               bc_h2(b2h.x), bc_h2(b2h.y), bc_h2(b2h.z), bc_h2(b2h.w) };
            #pragma unroll
            for (int i = 0; i < 8; i++)
                #pragma unroll
                for (int j = 0; j < 8; j++) {
                    acc[i][j] = fdot2(av1[i], bv1[j], acc[i][j]);   // +nv1_i.nv2_j
                    acc[i][j] = fdot2(av2[i], bv2[j], acc[i][j]);   // -nv2_i.nv1_j
                }
        }

        // p = poly(tanh(x)); upper = max(p,0), mirror = max(-p,0)
        #pragma unroll
        for (int i = 0; i < 8; i++)
            #pragma unroll
            for (int j = 0; j < 8; j++)
                acc[i][j] = poly_tanh01(fast_tanh(acc[i][j]));

        float* obase = out + (size_t)b * S2;
        #pragma unroll
        for (int i = 0; i < 8; i++) {
            int r = ti * TILE + ((i < 4) ? (ty * 4 + i) : (60 + ty * 4 + i));
            float4 v0 = { fmaxf(acc[i][0], 0.f), fmaxf(acc[i][1], 0.f),
                          fmaxf(acc[i][2], 0.f), fmaxf(acc[i][3], 0.f) };
            float4 v1 = { fmaxf(acc[i][4], 0.f), fmaxf(acc[i][5], 0.f),
                          fmaxf(acc[i][6], 0.f), fmaxf(acc[i][7], 0.f) };
            *(float4*)(obase + (size_t)r * NTOT + tj * TILE + tx * 4)      = v0;
            *(float4*)(obase + (size_t)r * NTOT + tj * TILE + 64 + tx * 4) = v1;
        }
        if (ti != tj) {
            #pragma unroll
            for (int j = 0; j < 8; j++) {
                int r = tj * TILE + ((j < 4) ? (tx * 4 + j) : (60 + tx * 4 + j));
                float4 v0 = { fmaxf(-acc[0][j], 0.f), fmaxf(-acc[1][j], 0.f),
                              fmaxf(-acc[2][j], 0.f), fmaxf(-acc[3][j], 0.f) };
                float4 v1 = { fmaxf(-acc[4][j], 0.f), fmaxf(-acc[5][j], 0.f),
                              fmaxf(-acc[6][j], 0.f), fmaxf(-acc[7][j], 0.f) };
                *(float4*)(obase + (size_t)r * NTOT + ti * TILE + ty * 4)      = v0;
                *(float4*)(obase + (size_t)r * NTOT + ti * TILE + 64 + ty * 4) = v1;
            }
        }
    } else if (blk < SS_BLOCKS + ST_BLOCKS) {
        const float* s_st1 = ws + WS_SST1;
        const float* s_st2 = ws + WS_SST2;
        int idx = (blk - SS_BLOCKS) * 256 + tid;
        int t4  = idx % (NT / 4);
        int row = idx / (NT / 4);
        int b   = row >> 11;
        int n   = row & (NS - 1);
        float  s1 = s_st1[row];
        float4 s2 = *(const float4*)(s_st2 + b * NT + t4 * 4);
        float4 v  = { f_out(s1 + s2.x), f_out(s1 + s2.y), f_out(s1 + s2.z), f_out(s1 + s2.w) };
        *(float4*)(out + (size_t)b * S2 + (size_t)n * NTOT + NS + t4 * 4) = v;
    } else if (blk < SS_BLOCKS + ST_BLOCKS + TS_BLOCKS) {
        const float* s_ts1 = ws + WS_STS1;
        const float* s_ts2 = ws + WS_STS2;
        int idx = (blk - SS_BLOCKS - ST_BLOCKS) * 256 + tid;
        int n4  = idx & 511;
        int row = idx >> 9;
        int b   = row / NT;
        int t   = row - b * NT;
        float  s1 = s_ts1[row];
        float4 s2 = *(const float4*)(s_ts2 + b * NS + n4 * 4);
        float4 v  = { f_out(s1 + s2.x), f_out(s1 + s2.y), f_out(s1 + s2.z), f_out(s1 + s2.w) };
        *(float4*)(out + (size_t)b * S2 + (size_t)(NS + t) * NTOT + n4 * 4) = v;
    } else {
        int idx = (blk - SS_BLOCKS - ST_BLOCKS - TS_BLOCKS) * 256 + tid;
        int j   = idx % NT;
        int rem = idx / NT;
        int i   = rem % NT;
        int b   = rem / NT;
        float o = 0.f;
        if (j >= i) {
            const float4* ri = (const float4*)(T + (b * NT + i) * DD);
            const float4* rj = (const float4*)(T + (b * NT + j) * DD);
            float acc = 0.f;
            #pragma unroll
            for (int q = 0; q < 8; q++) {
                float4 a = ri[q], c = rj[q];
                acc = fmaf(a.x, c.x, acc); acc = fmaf(a.y, c.y, acc);
                acc = fmaf(a.z, c.z, acc); acc = fmaf(a.w, c.w, acc);
            }
            o = f_out(acc);
        }
        out[(size_t)b * S2 + (size_t)(NS + i) * NTOT + NS + j] = o;
    }
}

extern "C" void kernel_launch(void* const* d_in, const int* in_sizes, int n_in,
                              void* d_out, int out_size, void* d_ws, size_t ws_size,
                              hipStream_t stream) {
    const float* S    = (const float*)d_in[0];
    const float* T    = (const float*)d_in[1];
    const float* W1   = (const float*)d_in[2];
    const float* W2   = (const float*)d_in[3];
    const float* w_st = (const float*)d_in[4];
    const float* b_st = (const float*)d_in[5];
    const float* w_ts = (const float*)d_in[6];
    const float* b_ts = (const float*)d_in[7];
    float* out = (float*)d_out;
    float* ws  = (float*)d_ws;

    precompute_kernel<<<37, 256, 0, stream>>>(S, T, W1, W2, w_st, b_st, w_ts, b_ts, ws);
    mega_kernel<<<GRID_BLOCKS, 256, 0, stream>>>(ws, T, out);
}